// Round 5
// baseline (209.916 us; speedup 1.0000x reference)
//
#include <hip/hip_runtime.h>
#include <stdint.h>

#define TPB 256
#define MMB 1024        // minmax grid blocks (also # of mm partial pairs)
#define SCB 2048        // score grid blocks (one chunk per wave at full residency)
#define WELEM 1024      // elements per wave-chunk
#define NG8 (WELEM / 32) // 32-elem groups per chunk

// d_ws float layout:
//  [OFF_MM + 2b]          : minmax block partials {min,max}, b = 0..mmb-1
//  [OFF_PART + b*128 + k] : per-score-block partial loss sums
#define OFF_MM     256
#define OFF_PART   4096

__global__ __launch_bounds__(TPB) void k_minmax(const float* __restrict__ x, int n,
                                                float* __restrict__ mm) {
    int n4 = n >> 2;
    const float4* x4 = (const float4*)x;
    float mn = INFINITY, mx = -INFINITY;
    int idx = blockIdx.x * TPB + threadIdx.x;
    int stride = gridDim.x * TPB;
    for (int i = idx; i < n4; i += stride) {
        float4 v = x4[i];
        mn = fminf(mn, fminf(fminf(v.x, v.y), fminf(v.z, v.w)));
        mx = fmaxf(mx, fmaxf(fmaxf(v.x, v.y), fmaxf(v.z, v.w)));
    }
    for (int i = (n4 << 2) + idx; i < n; i += stride) {
        float v = x[i];
        mn = fminf(mn, v);
        mx = fmaxf(mx, v);
    }
    #pragma unroll
    for (int m = 32; m; m >>= 1) {
        mn = fminf(mn, __shfl_xor(mn, m, 64));
        mx = fmaxf(mx, __shfl_xor(mx, m, 64));
    }
    __shared__ float smn[4], smx[4];
    int wv = threadIdx.x >> 6;
    if ((threadIdx.x & 63) == 0) { smn[wv] = mn; smx[wv] = mx; }
    __syncthreads();
    if (threadIdx.x == 0) {
        mn = fminf(fminf(smn[0], smn[1]), fminf(smn[2], smn[3]));
        mx = fmaxf(fmaxf(smx[0], smx[1]), fmaxf(smx[2], smx[3]));
        mm[2 * blockIdx.x + 0] = mn;
        mm[2 * blockIdx.x + 1] = mx;
    }
}

// exact reference fp32 order; must be IDENTICAL in k_score and k_final
__device__ __forceinline__ float4 cand_params(int k, float xmin, float xmax,
                                              float* nmin_out, float* nmax_out) {
    float xrange = xmax - xmin;
    int ii = k >> 4;                       // 0..7  (i = ii+1)
    float zpf = (float)(k & 15);
    float tmp_max = xrange / 8.0f * (float)(ii + 1);
    float tmp_delta = tmp_max / 15.0f;
    float shift = zpf * tmp_delta;
    float new_min = fmaxf(0.0f - shift, xmin);
    float new_max = fminf(tmp_max - shift, xmax);
    float min_neg = fminf(new_min, 0.0f);
    float max_pos = fmaxf(new_max, 0.0f);
    float scale = fmaxf((max_pos - min_neg) / 15.0f, 1e-8f);
    float zp = 0.0f - rintf(min_neg / scale);
    zp = fminf(fmaxf(zp, 0.0f), 15.0f);
    float4 p;
    p.x = 1.0f / scale;      // inv_s
    p.y = scale;             // s
    p.z = 0.0f - zp;         // lo
    p.w = 15.0f - zp;        // hi
    *nmin_out = new_min;
    *nmax_out = new_max;
    return p;
}

#define QUANT1(xv) { \
    float t0_ = (xv) * p0.x; float r0_ = rintf(t0_); \
    float c0_ = __builtin_amdgcn_fmed3f(r0_, p0.z, p0.w); \
    float d0_ = __builtin_fmaf(c0_, p0.y, -(xv)); \
    a0 = __builtin_fmaf(d0_, d0_, a0); \
    float t1_ = (xv) * p1.x; float r1_ = rintf(t1_); \
    float c1_ = __builtin_amdgcn_fmed3f(r1_, p1.z, p1.w); \
    float d1_ = __builtin_fmaf(c1_, p1.y, -(xv)); \
    a1 = __builtin_fmaf(d1_, d1_, a1); }
#define QUANT4(V) { QUANT1(V.x) QUANT1(V.y) QUANT1(V.z) QUANT1(V.w) }
#define COMP8(V0,V1,V2,V3,V4,V5,V6,V7) { QUANT4(V0) QUANT4(V1) QUANT4(V2) QUANT4(V3) \
                                         QUANT4(V4) QUANT4(V5) QUANT4(V6) QUANT4(V7) }
#define LOAD8(P,V0,V1,V2,V3,V4,V5,V6,V7) { V0=(P)[0];V1=(P)[1];V2=(P)[2];V3=(P)[3]; \
                                           V4=(P)[4];V5=(P)[5];V6=(P)[6];V7=(P)[7]; }

// candidate-per-lane scoring, TLP version: one 1024-elem chunk per wave at
// full occupancy (8 blocks/CU via launch_bounds(256,8) -> <=64 VGPR). Simple
// single-buffer loop: per-group latency stalls are hidden by 8 waves/SIMD,
// not by software prefetch (which the allocator kept defeating).
__global__ __launch_bounds__(TPB, 8) void k_score(const float* __restrict__ x, int n,
                                                  const float* __restrict__ mm, int mmb,
                                                  float* __restrict__ part, int nwc) {
    __shared__ float wsum[4][128];
    __shared__ float smn[4], smx[4];
    int tid = threadIdx.x, lane = tid & 63;
    int wv = __builtin_amdgcn_readfirstlane(threadIdx.x >> 6);

    // block-local reduce of minmax partials (order-free: fmin/fmax exact)
    float mn = INFINITY, mx = -INFINITY;
    for (int e = tid; e < mmb; e += TPB) {
        mn = fminf(mn, mm[2 * e + 0]);
        mx = fmaxf(mx, mm[2 * e + 1]);
    }
    #pragma unroll
    for (int m = 32; m; m >>= 1) {
        mn = fminf(mn, __shfl_xor(mn, m, 64));
        mx = fmaxf(mx, __shfl_xor(mx, m, 64));
    }
    if (lane == 0) { smn[wv] = mn; smx[wv] = mx; }
    __syncthreads();
    float xmin = fminf(fminf(smn[0], smn[1]), fminf(smn[2], smn[3]));
    float xmax = fmaxf(fmaxf(smx[0], smx[1]), fmaxf(smx[2], smx[3]));
    float dum0, dum1;
    float4 p0 = cand_params(2 * lane + 0, xmin, xmax, &dum0, &dum1);
    float4 p1 = cand_params(2 * lane + 1, xmin, xmax, &dum0, &dum1);
    float a0 = 0.0f, a1 = 0.0f;
    long nl = (long)n;

    // divergence decoy: VGPR zero the compiler can't prove uniform
    // (keeps the broadcast x-reads on the vector memory path)
    int lzero;
    asm("v_mov_b32 %0, 0" : "=v"(lzero));

    for (int wc = blockIdx.x * 4 + wv; wc < nwc; wc += gridDim.x * 4) {
        long base = (long)wc * WELEM;
        if (base + WELEM <= nl) {
            const float4* __restrict__ xp = (const float4*)(x + base) + lzero;
            #pragma unroll 1
            for (int g = 0; g < NG8; ++g) {
                float4 A0,A1,A2,A3,A4,A5,A6,A7;
                const float4* q = xp + g * 8;
                LOAD8(q, A0,A1,A2,A3,A4,A5,A6,A7)
                COMP8(A0,A1,A2,A3,A4,A5,A6,A7)
            }
        } else {
            for (long e = base; e < base + WELEM; ++e) {
                float xv = (e < nl) ? x[e] : 0.0f;  // pad scores 0 everywhere
                QUANT1(xv)
            }
        }
    }
    wsum[wv][2 * lane + 0] = a0;
    wsum[wv][2 * lane + 1] = a1;
    __syncthreads();
    if (tid < 128) {
        part[(long)blockIdx.x * 128 + tid] =
            (wsum[0][tid] + wsum[1][tid]) + (wsum[2][tid] + wsum[3][tid]);
    }
}

// 1 block, 1024 threads: recompute params (nmin/nmax), deterministic reduce of
// partials (fixed slice order), uint64 (score_bits<<32|k) min == strict-< argmin.
__global__ void k_final(const float* __restrict__ mm, int mmb,
                        const float* __restrict__ part, int nblk,
                        float* __restrict__ out) {
    __shared__ float sjs[128][8];
    __shared__ float sc[128];
    __shared__ float snmin[128], snmax[128];
    __shared__ float smn[16], smx[16];
    __shared__ unsigned long long wmin[16];
    int t = threadIdx.x;

    // reduce mm partials
    float mn = INFINITY, mx = -INFINITY;
    for (int e = t; e < mmb; e += 1024) {
        mn = fminf(mn, mm[2 * e + 0]);
        mx = fmaxf(mx, mm[2 * e + 1]);
    }
    #pragma unroll
    for (int m = 32; m; m >>= 1) {
        mn = fminf(mn, __shfl_xor(mn, m, 64));
        mx = fmaxf(mx, __shfl_xor(mx, m, 64));
    }
    int wv = t >> 6;
    if ((t & 63) == 0) { smn[wv] = mn; smx[wv] = mx; }
    __syncthreads();
    if (t < 128) {
        float xmin = smn[0], xmax = smx[0];
        #pragma unroll
        for (int w = 1; w < 16; ++w) {
            xmin = fminf(xmin, smn[w]);
            xmax = fmaxf(xmax, smx[w]);
        }
        float nmi, nma;
        (void)cand_params(t, xmin, xmax, &nmi, &nma);
        snmin[t] = nmi;
        snmax[t] = nma;
    }

    // reduce per-block loss partials: candidate k = t>>3, slice j = t&7
    int k = t >> 3, j = t & 7;
    float s = 0.0f;
    for (int b = j; b < nblk; b += 8) s += part[(long)b * 128 + k];
    sjs[k][j] = s;
    __syncthreads();
    if (j == 0) {
        sc[k] = ((sjs[k][0] + sjs[k][1]) + (sjs[k][2] + sjs[k][3]))
              + ((sjs[k][4] + sjs[k][5]) + (sjs[k][6] + sjs[k][7]));
    }
    __syncthreads();
    unsigned long long key = ~0ull;
    if (t < 128) {
        key = (((unsigned long long)__float_as_uint(sc[t])) << 32) | (unsigned)t;
    }
    #pragma unroll
    for (int m = 32; m; m >>= 1) {
        unsigned long long o = __shfl_xor(key, m, 64);
        key = (o < key) ? o : key;
    }
    if ((t & 63) == 0) wmin[wv] = key;
    __syncthreads();
    if (t == 0) {
        unsigned long long best = wmin[0];
        for (int w = 1; w < 16; ++w) if (wmin[w] < best) best = wmin[w];
        int bk = (int)(best & 0x7fu);
        out[0] = snmin[bk];
        out[1] = snmax[bk];
    }
}

extern "C" void kernel_launch(void* const* d_in, const int* in_sizes, int n_in,
                              void* d_out, int out_size, void* d_ws, size_t ws_size,
                              hipStream_t stream) {
    const float* x = (const float*)d_in[0];
    int n = in_sizes[0];
    float* out = (float*)d_out;
    float* W = (float*)d_ws;

    int n4 = n >> 2;
    int mmb = (n4 + TPB - 1) / TPB;
    if (mmb > MMB) mmb = MMB;
    if (mmb < 1) mmb = 1;

    long maxblk_l = ((long)(ws_size / 4) - OFF_PART) / 128;
    int scb = SCB;
    if (maxblk_l < (long)scb) scb = (int)(maxblk_l < 1 ? 1 : maxblk_l);
    int nwc = (n + WELEM - 1) / WELEM;
    int minblk = (nwc + 3) / 4;
    if (scb > minblk) scb = minblk;   // no empty blocks
    if (scb < 1) scb = 1;

    k_minmax<<<mmb, TPB, 0, stream>>>(x, n, W + OFF_MM);
    k_score<<<scb, TPB, 0, stream>>>(x, n, W + OFF_MM, mmb, W + OFF_PART, nwc);
    k_final<<<1, 1024, 0, stream>>>(W + OFF_MM, mmb, W + OFF_PART, scb, out);
}

// Round 6
// 199.679 us; speedup vs baseline: 1.0513x; 1.0513x over previous
//
#include <hip/hip_runtime.h>
#include <stdint.h>

#define TPB 256
#define MMB 1024        // minmax grid blocks (also # of mm partial pairs)
#define SCB 2048        // score grid blocks: 8192 waves = 1 chunk/wave, 8 blk/CU
#define WELEM 1024      // elements per wave-chunk
#define NG (WELEM / 32) // 32-elem groups per chunk

// d_ws float layout:
//  [OFF_MM + 2b]          : minmax block partials {min,max}, b = 0..mmb-1
//  [OFF_PART + b*128 + k] : per-score-block partial loss sums
#define OFF_MM     256
#define OFF_PART   4096

__global__ __launch_bounds__(TPB) void k_minmax(const float* __restrict__ x, int n,
                                                float* __restrict__ mm) {
    int n4 = n >> 2;
    const float4* x4 = (const float4*)x;
    float mn = INFINITY, mx = -INFINITY;
    int idx = blockIdx.x * TPB + threadIdx.x;
    int stride = gridDim.x * TPB;
    for (int i = idx; i < n4; i += stride) {
        float4 v = x4[i];
        mn = fminf(mn, fminf(fminf(v.x, v.y), fminf(v.z, v.w)));
        mx = fmaxf(mx, fmaxf(fmaxf(v.x, v.y), fmaxf(v.z, v.w)));
    }
    for (int i = (n4 << 2) + idx; i < n; i += stride) {
        float v = x[i];
        mn = fminf(mn, v);
        mx = fmaxf(mx, v);
    }
    #pragma unroll
    for (int m = 32; m; m >>= 1) {
        mn = fminf(mn, __shfl_xor(mn, m, 64));
        mx = fmaxf(mx, __shfl_xor(mx, m, 64));
    }
    __shared__ float smn[4], smx[4];
    int wv = threadIdx.x >> 6;
    if ((threadIdx.x & 63) == 0) { smn[wv] = mn; smx[wv] = mx; }
    __syncthreads();
    if (threadIdx.x == 0) {
        mn = fminf(fminf(smn[0], smn[1]), fminf(smn[2], smn[3]));
        mx = fmaxf(fmaxf(smx[0], smx[1]), fmaxf(smx[2], smx[3]));
        mm[2 * blockIdx.x + 0] = mn;
        mm[2 * blockIdx.x + 1] = mx;
    }
}

// exact reference fp32 order; must be IDENTICAL in k_score and k_final
__device__ __forceinline__ float4 cand_params(int k, float xmin, float xmax,
                                              float* nmin_out, float* nmax_out) {
    float xrange = xmax - xmin;
    int ii = k >> 4;                       // 0..7  (i = ii+1)
    float zpf = (float)(k & 15);
    float tmp_max = xrange / 8.0f * (float)(ii + 1);
    float tmp_delta = tmp_max / 15.0f;
    float shift = zpf * tmp_delta;
    float new_min = fmaxf(0.0f - shift, xmin);
    float new_max = fminf(tmp_max - shift, xmax);
    float min_neg = fminf(new_min, 0.0f);
    float max_pos = fmaxf(new_max, 0.0f);
    float scale = fmaxf((max_pos - min_neg) / 15.0f, 1e-8f);
    float zp = 0.0f - rintf(min_neg / scale);
    zp = fminf(fmaxf(zp, 0.0f), 15.0f);
    float4 p;
    p.x = 1.0f / scale;      // inv_s
    p.y = scale;             // s
    p.z = 0.0f - zp;         // lo
    p.w = 15.0f - zp;        // hi
    *nmin_out = new_min;
    *nmax_out = new_max;
    return p;
}

#define QUANT1(xv) { \
    float t0_ = (xv) * p0.x; float r0_ = rintf(t0_); \
    float c0_ = __builtin_amdgcn_fmed3f(r0_, p0.z, p0.w); \
    float d0_ = __builtin_fmaf(c0_, p0.y, -(xv)); \
    a0 = __builtin_fmaf(d0_, d0_, a0); \
    float t1_ = (xv) * p1.x; float r1_ = rintf(t1_); \
    float c1_ = __builtin_amdgcn_fmed3f(r1_, p1.z, p1.w); \
    float d1_ = __builtin_fmaf(c1_, p1.y, -(xv)); \
    a1 = __builtin_fmaf(d1_, d1_, a1); }
#define QUANT4(V) { QUANT1(V.x) QUANT1(V.y) QUANT1(V.z) QUANT1(V.w) }
#define COMP8(V0,V1,V2,V3,V4,V5,V6,V7) { QUANT4(V0) QUANT4(V1) QUANT4(V2) QUANT4(V3) \
                                         QUANT4(V4) QUANT4(V5) QUANT4(V6) QUANT4(V7) }
#define LOAD8(P,V0,V1,V2,V3,V4,V5,V6,V7) { V0=(P)[0];V1=(P)[1];V2=(P)[2];V3=(P)[3]; \
                                           V4=(P)[4];V5=(P)[5];V6=(P)[6];V7=(P)[7]; }

// candidate-per-lane scoring, scalar-broadcast + full-TLP version: addresses
// are wave-uniform so the compiler scalarizes the x-loads (s_load -> SGPRs,
// VGPR stays ~20 -> no spills at 8 blk/CU). One 1024-elem chunk per wave at
// full residency; lgkmcnt-ahead s_loads + 8 waves/SIMD hide latency.
__global__ __launch_bounds__(TPB, 8) void k_score(const float* __restrict__ x, int n,
                                                  const float* __restrict__ mm, int mmb,
                                                  float* __restrict__ part, int nwc) {
    __shared__ float wsum[4][128];
    __shared__ float smn[4], smx[4];
    int tid = threadIdx.x, lane = tid & 63;
    int wv = __builtin_amdgcn_readfirstlane(threadIdx.x >> 6);

    // block-local reduce of minmax partials (order-free: fmin/fmax exact)
    float mn = INFINITY, mx = -INFINITY;
    for (int e = tid; e < mmb; e += TPB) {
        mn = fminf(mn, mm[2 * e + 0]);
        mx = fmaxf(mx, mm[2 * e + 1]);
    }
    #pragma unroll
    for (int m = 32; m; m >>= 1) {
        mn = fminf(mn, __shfl_xor(mn, m, 64));
        mx = fmaxf(mx, __shfl_xor(mx, m, 64));
    }
    if (lane == 0) { smn[wv] = mn; smx[wv] = mx; }
    __syncthreads();
    float xmin = fminf(fminf(smn[0], smn[1]), fminf(smn[2], smn[3]));
    float xmax = fmaxf(fmaxf(smx[0], smx[1]), fmaxf(smx[2], smx[3]));
    float dum0, dum1;
    float4 p0 = cand_params(2 * lane + 0, xmin, xmax, &dum0, &dum1);
    float4 p1 = cand_params(2 * lane + 1, xmin, xmax, &dum0, &dum1);
    float a0 = 0.0f, a1 = 0.0f;
    long nl = (long)n;

    for (int wc = blockIdx.x * 4 + wv; wc < nwc; wc += gridDim.x * 4) {
        long base = (long)wc * WELEM;
        if (base + WELEM <= nl) {
            const float4* __restrict__ xp = (const float4*)(x + base);
            float4 A0,A1,A2,A3,A4,A5,A6,A7;
            float4 B0,B1,B2,B3,B4,B5,B6,B7;
            LOAD8(xp, A0,A1,A2,A3,A4,A5,A6,A7)
            #pragma unroll 1
            for (int g = 0; g < NG; g += 2) {
                const float4* q1 = xp + (g + 1) * 8;
                LOAD8(q1, B0,B1,B2,B3,B4,B5,B6,B7)
                COMP8(A0,A1,A2,A3,A4,A5,A6,A7)
                int g2 = (g + 2 < NG) ? (g + 2) : (NG - 1);  // harmless reload on last iter
                const float4* q2 = xp + g2 * 8;
                LOAD8(q2, A0,A1,A2,A3,A4,A5,A6,A7)
                COMP8(B0,B1,B2,B3,B4,B5,B6,B7)
            }
        } else {
            for (long e = base; e < base + WELEM; ++e) {
                float xv = (e < nl) ? x[e] : 0.0f;  // pad scores 0 everywhere
                QUANT1(xv)
            }
        }
    }
    wsum[wv][2 * lane + 0] = a0;
    wsum[wv][2 * lane + 1] = a1;
    __syncthreads();
    if (tid < 128) {
        part[(long)blockIdx.x * 128 + tid] =
            (wsum[0][tid] + wsum[1][tid]) + (wsum[2][tid] + wsum[3][tid]);
    }
}

// 1 block, 1024 threads: recompute params (nmin/nmax), deterministic reduce of
// partials (fixed slice order), uint64 (score_bits<<32|k) min == strict-< argmin.
__global__ void k_final(const float* __restrict__ mm, int mmb,
                        const float* __restrict__ part, int nblk,
                        float* __restrict__ out) {
    __shared__ float sjs[128][8];
    __shared__ float sc[128];
    __shared__ float snmin[128], snmax[128];
    __shared__ float smn[16], smx[16];
    __shared__ unsigned long long wmin[16];
    int t = threadIdx.x;

    // reduce mm partials
    float mn = INFINITY, mx = -INFINITY;
    for (int e = t; e < mmb; e += 1024) {
        mn = fminf(mn, mm[2 * e + 0]);
        mx = fmaxf(mx, mm[2 * e + 1]);
    }
    #pragma unroll
    for (int m = 32; m; m >>= 1) {
        mn = fminf(mn, __shfl_xor(mn, m, 64));
        mx = fmaxf(mx, __shfl_xor(mx, m, 64));
    }
    int wv = t >> 6;
    if ((t & 63) == 0) { smn[wv] = mn; smx[wv] = mx; }
    __syncthreads();
    if (t < 128) {
        float xmin = smn[0], xmax = smx[0];
        #pragma unroll
        for (int w = 1; w < 16; ++w) {
            xmin = fminf(xmin, smn[w]);
            xmax = fmaxf(xmax, smx[w]);
        }
        float nmi, nma;
        (void)cand_params(t, xmin, xmax, &nmi, &nma);
        snmin[t] = nmi;
        snmax[t] = nma;
    }

    // reduce per-block loss partials: candidate k = t>>3, slice j = t&7
    int k = t >> 3, j = t & 7;
    float s = 0.0f;
    for (int b = j; b < nblk; b += 8) s += part[(long)b * 128 + k];
    sjs[k][j] = s;
    __syncthreads();
    if (j == 0) {
        sc[k] = ((sjs[k][0] + sjs[k][1]) + (sjs[k][2] + sjs[k][3]))
              + ((sjs[k][4] + sjs[k][5]) + (sjs[k][6] + sjs[k][7]));
    }
    __syncthreads();
    unsigned long long key = ~0ull;
    if (t < 128) {
        key = (((unsigned long long)__float_as_uint(sc[t])) << 32) | (unsigned)t;
    }
    #pragma unroll
    for (int m = 32; m; m >>= 1) {
        unsigned long long o = __shfl_xor(key, m, 64);
        key = (o < key) ? o : key;
    }
    if ((t & 63) == 0) wmin[wv] = key;
    __syncthreads();
    if (t == 0) {
        unsigned long long best = wmin[0];
        for (int w = 1; w < 16; ++w) if (wmin[w] < best) best = wmin[w];
        int bk = (int)(best & 0x7fu);
        out[0] = snmin[bk];
        out[1] = snmax[bk];
    }
}

extern "C" void kernel_launch(void* const* d_in, const int* in_sizes, int n_in,
                              void* d_out, int out_size, void* d_ws, size_t ws_size,
                              hipStream_t stream) {
    const float* x = (const float*)d_in[0];
    int n = in_sizes[0];
    float* out = (float*)d_out;
    float* W = (float*)d_ws;

    int n4 = n >> 2;
    int mmb = (n4 + TPB - 1) / TPB;
    if (mmb > MMB) mmb = MMB;
    if (mmb < 1) mmb = 1;

    long maxblk_l = ((long)(ws_size / 4) - OFF_PART) / 128;
    int scb = SCB;
    if (maxblk_l < (long)scb) scb = (int)(maxblk_l < 1 ? 1 : maxblk_l);
    int nwc = (n + WELEM - 1) / WELEM;
    int minblk = (nwc + 3) / 4;
    if (scb > minblk) scb = minblk;   // no empty blocks
    if (scb < 1) scb = 1;

    k_minmax<<<mmb, TPB, 0, stream>>>(x, n, W + OFF_MM);
    k_score<<<scb, TPB, 0, stream>>>(x, n, W + OFF_MM, mmb, W + OFF_PART, nwc);
    k_final<<<1, 1024, 0, stream>>>(W + OFF_MM, mmb, W + OFF_PART, scb, out);
}

// Round 7
// 132.930 us; speedup vs baseline: 1.5791x; 1.5021x over previous
//
#include <hip/hip_runtime.h>
#include <stdint.h>

#define TPB 256
#define MMB 1024        // minmax grid blocks (also # of mm partial pairs)
#define SCB 1536        // score grid: 6 blocks/CU x 256 CU resident
#define WELEM 256       // elements per wave-chunk (one float4 per lane staged)

// d_ws float layout:
//  [OFF_MM + 2b]         : minmax block partials {min,max}, b = 0..mmb-1
//  [OFF_SCORES + k]      : final per-candidate scores, k = 0..127
//  [OFF_PART + k*nblk+b] : per-candidate per-block partial sums (TRANSPOSED)
#define OFF_MM     256
#define OFF_SCORES 2304
#define OFF_PART   4096

__global__ __launch_bounds__(TPB) void k_minmax(const float* __restrict__ x, int n,
                                                float* __restrict__ mm) {
    int n4 = n >> 2;
    const float4* x4 = (const float4*)x;
    float mn = INFINITY, mx = -INFINITY;
    int idx = blockIdx.x * TPB + threadIdx.x;
    int stride = gridDim.x * TPB;
    for (int i = idx; i < n4; i += stride) {
        float4 v = x4[i];
        mn = fminf(mn, fminf(fminf(v.x, v.y), fminf(v.z, v.w)));
        mx = fmaxf(mx, fmaxf(fmaxf(v.x, v.y), fmaxf(v.z, v.w)));
    }
    for (int i = (n4 << 2) + idx; i < n; i += stride) {
        float v = x[i];
        mn = fminf(mn, v);
        mx = fmaxf(mx, v);
    }
    #pragma unroll
    for (int m = 32; m; m >>= 1) {
        mn = fminf(mn, __shfl_xor(mn, m, 64));
        mx = fmaxf(mx, __shfl_xor(mx, m, 64));
    }
    __shared__ float smn[4], smx[4];
    int wv = threadIdx.x >> 6;
    if ((threadIdx.x & 63) == 0) { smn[wv] = mn; smx[wv] = mx; }
    __syncthreads();
    if (threadIdx.x == 0) {
        mn = fminf(fminf(smn[0], smn[1]), fminf(smn[2], smn[3]));
        mx = fmaxf(fmaxf(smx[0], smx[1]), fmaxf(smx[2], smx[3]));
        mm[2 * blockIdx.x + 0] = mn;
        mm[2 * blockIdx.x + 1] = mx;
    }
}

// exact reference fp32 order; must be IDENTICAL in k_score and k_argmin
__device__ __forceinline__ float4 cand_params(int k, float xmin, float xmax,
                                              float* nmin_out, float* nmax_out) {
    float xrange = xmax - xmin;
    int ii = k >> 4;                       // 0..7  (i = ii+1)
    float zpf = (float)(k & 15);
    float tmp_max = xrange / 8.0f * (float)(ii + 1);
    float tmp_delta = tmp_max / 15.0f;
    float shift = zpf * tmp_delta;
    float new_min = fmaxf(0.0f - shift, xmin);
    float new_max = fminf(tmp_max - shift, xmax);
    float min_neg = fminf(new_min, 0.0f);
    float max_pos = fmaxf(new_max, 0.0f);
    float scale = fmaxf((max_pos - min_neg) / 15.0f, 1e-8f);
    float zp = 0.0f - rintf(min_neg / scale);
    zp = fminf(fmaxf(zp, 0.0f), 15.0f);
    float4 p;
    p.x = 1.0f / scale;      // inv_s
    p.y = scale;             // s
    p.z = 0.0f - zp;         // lo
    p.w = 15.0f - zp;        // hi
    *nmin_out = new_min;
    *nmax_out = new_max;
    return p;
}

#define QUANT1(xv) { \
    float t0_ = (xv) * p0.x; float r0_ = rintf(t0_); \
    float c0_ = __builtin_amdgcn_fmed3f(r0_, p0.z, p0.w); \
    float d0_ = __builtin_fmaf(c0_, p0.y, -(xv)); \
    a0 = __builtin_fmaf(d0_, d0_, a0); \
    float t1_ = (xv) * p1.x; float r1_ = rintf(t1_); \
    float c1_ = __builtin_amdgcn_fmed3f(r1_, p1.z, p1.w); \
    float d1_ = __builtin_fmaf(c1_, p1.y, -(xv)); \
    a1 = __builtin_fmaf(d1_, d1_, a1); }
#define QUANT4(V) { QUANT1(V.x) QUANT1(V.y) QUANT1(V.z) QUANT1(V.w) }

// candidate-per-lane scoring via LDS broadcast staging at high occupancy.
// Each wave stages one 256-elem chunk (1 float4/lane, 1 KB) into its private
// LDS region, then all 64 lanes re-read it with uniform-address ds_read_b128
// (hardware broadcast, conflict-free). Data never needs a big register buffer
// (VGPR ~45, no spills) and 6 KB LDS/block leaves occupancy at 6 blocks/CU.
__global__ __launch_bounds__(TPB, 6) void k_score(const float* __restrict__ x, int n,
                                                  const float* __restrict__ mm, int mmb,
                                                  float* __restrict__ part, int nwc,
                                                  int nblk) {
    __shared__ float ls[4][WELEM];       // 4 KB, wave-private regions
    __shared__ float wsum[4][128];
    __shared__ float smn[4], smx[4];
    int tid = threadIdx.x, lane = tid & 63;
    int wv = __builtin_amdgcn_readfirstlane(threadIdx.x >> 6);

    // block-local reduce of minmax partials (order-free: fmin/fmax exact)
    float mn = INFINITY, mx = -INFINITY;
    for (int e = tid; e < mmb; e += TPB) {
        mn = fminf(mn, mm[2 * e + 0]);
        mx = fmaxf(mx, mm[2 * e + 1]);
    }
    #pragma unroll
    for (int m = 32; m; m >>= 1) {
        mn = fminf(mn, __shfl_xor(mn, m, 64));
        mx = fmaxf(mx, __shfl_xor(mx, m, 64));
    }
    if (lane == 0) { smn[wv] = mn; smx[wv] = mx; }
    __syncthreads();
    float xmin = fminf(fminf(smn[0], smn[1]), fminf(smn[2], smn[3]));
    float xmax = fmaxf(fmaxf(smx[0], smx[1]), fmaxf(smx[2], smx[3]));
    float dum0, dum1;
    float4 p0 = cand_params(2 * lane + 0, xmin, xmax, &dum0, &dum1);
    float4 p1 = cand_params(2 * lane + 1, xmin, xmax, &dum0, &dum1);
    float a0 = 0.0f, a1 = 0.0f;
    long nl = (long)n;

    float* lbuf = &ls[wv][0];
    int gw = blockIdx.x * 4 + wv;        // global wave id
    int nW = gridDim.x * 4;              // total waves

    for (int c = gw; c < nwc; c += nW) {
        long base = (long)c * WELEM;
        long e = base + (long)lane * 4;
        float4 v;
        if (base + WELEM <= nl) {
            v = *(const float4*)(x + e);
        } else {
            v.x = (e + 0 < nl) ? x[e + 0] : 0.0f;  // pad scores 0 everywhere
            v.y = (e + 1 < nl) ? x[e + 1] : 0.0f;
            v.z = (e + 2 < nl) ? x[e + 2] : 0.0f;
            v.w = (e + 3 < nl) ? x[e + 3] : 0.0f;
        }
        *(float4*)(lbuf + lane * 4) = v;
        // wave-private region: intra-wave write->read ordering only
        asm volatile("s_waitcnt lgkmcnt(0)" ::: "memory");
        __builtin_amdgcn_sched_barrier(0);

        const float4* l4 = (const float4*)lbuf;
        #pragma unroll 4
        for (int i = 0; i < WELEM / 4; ++i) {
            float4 u = l4[i];
            QUANT4(u)
        }
    }
    wsum[wv][2 * lane + 0] = a0;
    wsum[wv][2 * lane + 1] = a1;
    __syncthreads();
    if (tid < 128) {
        float s = (wsum[0][tid] + wsum[1][tid]) + (wsum[2][tid] + wsum[3][tid]);
        part[(long)tid * nblk + blockIdx.x] = s;   // transposed: candidate-major
    }
}

// 128 blocks x 256 threads: block k reduces its candidate's nblk partials
// (contiguous, coalesced) with a fixed deterministic tree.
__global__ __launch_bounds__(TPB) void k_red(const float* __restrict__ part, int nblk,
                                             float* __restrict__ scores) {
    __shared__ float red[TPB];
    int k = blockIdx.x, t = threadIdx.x;
    const float* p = part + (long)k * nblk;
    float s = 0.0f;
    for (int b = t; b < nblk; b += TPB) s += p[b];   // fixed per-thread order
    red[t] = s;
    __syncthreads();
    #pragma unroll
    for (int off = TPB / 2; off > 0; off >>= 1) {
        if (t < off) red[t] += red[t + off];         // fixed tree
        __syncthreads();
    }
    if (t == 0) scores[k] = red[0];
}

// 1 block, 128 threads: reduce mm partials, recompute params, strict-< argmin
// via uint64 (score_bits<<32|k) min (ties -> lowest k == first occurrence).
__global__ void k_argmin(const float* __restrict__ mm, int mmb,
                         const float* __restrict__ scores, float* __restrict__ out) {
    __shared__ float smn[2], smx[2];
    __shared__ unsigned long long wmin[2];
    int t = threadIdx.x;

    float mn = INFINITY, mx = -INFINITY;
    for (int e = t; e < mmb; e += 128) {
        mn = fminf(mn, mm[2 * e + 0]);
        mx = fmaxf(mx, mm[2 * e + 1]);
    }
    #pragma unroll
    for (int m = 32; m; m >>= 1) {
        mn = fminf(mn, __shfl_xor(mn, m, 64));
        mx = fmaxf(mx, __shfl_xor(mx, m, 64));
    }
    int wv = t >> 6;
    if ((t & 63) == 0) { smn[wv] = mn; smx[wv] = mx; }
    __syncthreads();
    float xmin = fminf(smn[0], smn[1]);
    float xmax = fmaxf(smx[0], smx[1]);

    float nmi, nma;
    (void)cand_params(t, xmin, xmax, &nmi, &nma);

    unsigned long long key =
        (((unsigned long long)__float_as_uint(scores[t])) << 32) | (unsigned)t;
    #pragma unroll
    for (int m = 32; m; m >>= 1) {
        unsigned long long o = __shfl_xor(key, m, 64);
        key = (o < key) ? o : key;
    }
    if ((t & 63) == 0) wmin[wv] = key;
    __syncthreads();
    unsigned long long best = (wmin[0] < wmin[1]) ? wmin[0] : wmin[1];
    int bk = (int)(best & 0x7fu);
    if (t == bk) {
        out[0] = nmi;
        out[1] = nma;
    }
}

extern "C" void kernel_launch(void* const* d_in, const int* in_sizes, int n_in,
                              void* d_out, int out_size, void* d_ws, size_t ws_size,
                              hipStream_t stream) {
    const float* x = (const float*)d_in[0];
    int n = in_sizes[0];
    float* out = (float*)d_out;
    float* W = (float*)d_ws;

    int n4 = n >> 2;
    int mmb = (n4 + TPB - 1) / TPB;
    if (mmb > MMB) mmb = MMB;
    if (mmb < 1) mmb = 1;

    long maxblk_l = ((long)(ws_size / 4) - OFF_PART) / 128;
    int scb = SCB;
    if (maxblk_l < (long)scb) scb = (int)(maxblk_l < 1 ? 1 : maxblk_l);
    int nwc = (n + WELEM - 1) / WELEM;
    int minblk = (nwc + 3) / 4;
    if (scb > minblk) scb = minblk;   // no empty blocks
    if (scb < 1) scb = 1;

    k_minmax<<<mmb, TPB, 0, stream>>>(x, n, W + OFF_MM);
    k_score<<<scb, TPB, 0, stream>>>(x, n, W + OFF_MM, mmb, W + OFF_PART, nwc, scb);
    k_red<<<128, TPB, 0, stream>>>(W + OFF_PART, scb, W + OFF_SCORES);
    k_argmin<<<1, 128, 0, stream>>>(W + OFF_MM, mmb, W + OFF_SCORES, out);
}

// Round 8
// 87.270 us; speedup vs baseline: 2.4054x; 1.5232x over previous
//
#include <hip/hip_runtime.h>
#include <stdint.h>

#define TPB 256
#define MMB 1024                 // minmax grid blocks / mm partial pairs
#define NBIN 2048                // histogram bins
#define FRACB 15                 // NBIN * 2^FRACB = 2^26 quantization of x-range
#define UMAX 67108863u           // 2^26 - 1
#define HB 1536                  // hist grid (6 blocks/CU at 24KB LDS)
#define RB 1024                  // rescore grid

// d_ws float-index layout (proven ws_size >= 528KB from earlier rounds; we use ~98KB):
//  [OFF_MM    + 2b]  : minmax block partials {min,max}, b < MMB
//  [OFF_TOP   + 4r]  : top-8 candidate params float4 {inv_s, s, lo, hi}
//  [OFF_TOPK  + r]   : top-8 candidate ids (u32)
//  [OFF_HCNT  + j]   : global histogram counts (u32[NBIN])
//  [OFF_HQS   + 2j]  : global histogram sum of 26-bit quantized offsets (u64[NBIN])
//  [OFF_RPART + b*8+c]: rescore per-block partials (f32[RB*8])
#define OFF_MM     256
#define OFF_TOP    2304
#define OFF_TOPK   2336
#define OFF_HCNT   4096
#define OFF_HQS    8192
#define OFF_RPART  16384

__global__ void k_zero(float* W) {
    int i = blockIdx.x * TPB + threadIdx.x;
    if (i < NBIN) {
        ((uint32_t*)(W + OFF_HCNT))[i] = 0u;
        ((unsigned long long*)(W + OFF_HQS))[i] = 0ull;
    }
}

__global__ __launch_bounds__(TPB) void k_minmax(const float* __restrict__ x, int n,
                                                float* __restrict__ mm) {
    int n4 = n >> 2;
    const float4* x4 = (const float4*)x;
    float mn = INFINITY, mx = -INFINITY;
    int idx = blockIdx.x * TPB + threadIdx.x;
    int stride = gridDim.x * TPB;
    for (int i = idx; i < n4; i += stride) {
        float4 v = x4[i];
        mn = fminf(mn, fminf(fminf(v.x, v.y), fminf(v.z, v.w)));
        mx = fmaxf(mx, fmaxf(fmaxf(v.x, v.y), fmaxf(v.z, v.w)));
    }
    for (int i = (n4 << 2) + idx; i < n; i += stride) {
        float v = x[i];
        mn = fminf(mn, v);
        mx = fmaxf(mx, v);
    }
    #pragma unroll
    for (int m = 32; m; m >>= 1) {
        mn = fminf(mn, __shfl_xor(mn, m, 64));
        mx = fmaxf(mx, __shfl_xor(mx, m, 64));
    }
    __shared__ float smn[4], smx[4];
    int wv = threadIdx.x >> 6;
    if ((threadIdx.x & 63) == 0) { smn[wv] = mn; smx[wv] = mx; }
    __syncthreads();
    if (threadIdx.x == 0) {
        mn = fminf(fminf(smn[0], smn[1]), fminf(smn[2], smn[3]));
        mx = fmaxf(fmaxf(smx[0], smx[1]), fmaxf(smx[2], smx[3]));
        mm[2 * blockIdx.x + 0] = mn;
        mm[2 * blockIdx.x + 1] = mx;
    }
}

// exact reference fp32 order; IDENTICAL wherever params are derived
__device__ __forceinline__ float4 cand_params(int k, float xmin, float xmax,
                                              float* nmin_out, float* nmax_out) {
    float xrange = xmax - xmin;
    int ii = k >> 4;                       // 0..7  (i = ii+1)
    float zpf = (float)(k & 15);
    float tmp_max = xrange / 8.0f * (float)(ii + 1);
    float tmp_delta = tmp_max / 15.0f;
    float shift = zpf * tmp_delta;
    float new_min = fmaxf(0.0f - shift, xmin);
    float new_max = fminf(tmp_max - shift, xmax);
    float min_neg = fminf(new_min, 0.0f);
    float max_pos = fmaxf(new_max, 0.0f);
    float scale = fmaxf((max_pos - min_neg) / 15.0f, 1e-8f);
    float zp = 0.0f - rintf(min_neg / scale);
    zp = fminf(fmaxf(zp, 0.0f), 15.0f);
    float4 p;
    p.x = 1.0f / scale;      // inv_s
    p.y = scale;             // s
    p.z = 0.0f - zp;         // lo
    p.w = 15.0f - zp;        // hi
    *nmin_out = new_min;
    *nmax_out = new_max;
    return p;
}

__device__ __forceinline__ void mm_reduce(const float* __restrict__ mm, int mmb,
                                          int tid, float* xmin_o, float* xmax_o) {
    __shared__ float smn[4], smx[4];
    float mn = INFINITY, mx = -INFINITY;
    for (int e = tid; e < mmb; e += TPB) {
        mn = fminf(mn, mm[2 * e + 0]);
        mx = fmaxf(mx, mm[2 * e + 1]);
    }
    #pragma unroll
    for (int m = 32; m; m >>= 1) {
        mn = fminf(mn, __shfl_xor(mn, m, 64));
        mx = fmaxf(mx, __shfl_xor(mx, m, 64));
    }
    int wv = tid >> 6;
    if ((tid & 63) == 0) { smn[wv] = mn; smx[wv] = mx; }
    __syncthreads();
    *xmin_o = fminf(fminf(smn[0], smn[1]), fminf(smn[2], smn[3]));
    *xmax_o = fmaxf(fmaxf(smx[0], smx[1]), fmaxf(smx[2], smx[3]));
}

// histogram build: U = 26-bit quantization of (x - xmin)/R; bin = U>>15.
// LDS per-block hist (u32 cnt, u64 sumU) with integer atomics only
// (order-free, bitwise deterministic), merged to global integer atomics.
__global__ __launch_bounds__(TPB) void k_hist(const float* __restrict__ x, int n,
                                              const float* __restrict__ mm, int mmb,
                                              float* __restrict__ W) {
    __shared__ uint32_t hc[NBIN];
    __shared__ unsigned long long hq[NBIN];
    int tid = threadIdx.x;
    for (int i = tid; i < NBIN; i += TPB) { hc[i] = 0u; hq[i] = 0ull; }
    float xmin, xmax;
    mm_reduce(mm, mmb, tid, &xmin, &xmax);   // contains the needed __syncthreads
    float R = xmax - xmin;
    float sf = 67108864.0f / R;              // 2^26 / R  (R==0 -> inf -> nan path safe)
    float c0 = 0.0f - xmin * sf;

    int n4 = n >> 2;
    const float4* x4 = (const float4*)x;
    int gtid = blockIdx.x * TPB + tid;
    int stride = gridDim.x * TPB;
    for (int i = gtid; i < n4; i += stride) {
        float4 v = x4[i];
        #pragma unroll
        for (int q = 0; q < 4; ++q) {
            float xv = (q == 0) ? v.x : (q == 1) ? v.y : (q == 2) ? v.z : v.w;
            float t = fmaxf(__builtin_fmaf(xv, sf, c0), 0.0f);
            uint32_t U = (uint32_t)t;        // v_cvt_u32_f32 (saturating)
            U = (U < UMAX) ? U : UMAX;
            atomicAdd(&hc[U >> FRACB], 1u);
            atomicAdd(&hq[U >> FRACB], (unsigned long long)U);
        }
    }
    for (int i = (n4 << 2) + gtid; i < n; i += stride) {
        float t = fmaxf(__builtin_fmaf(x[i], sf, c0), 0.0f);
        uint32_t U = (uint32_t)t;
        U = (U < UMAX) ? U : UMAX;
        atomicAdd(&hc[U >> FRACB], 1u);
        atomicAdd(&hq[U >> FRACB], (unsigned long long)U);
    }
    __syncthreads();
    uint32_t* HC = (uint32_t*)(W + OFF_HCNT);
    unsigned long long* HQ = (unsigned long long*)(W + OFF_HQS);
    for (int i = tid; i < NBIN; i += TPB) {
        if (hc[i]) atomicAdd(&HC[i], hc[i]);
        if (hq[i]) atomicAdd(&HQ[i], hq[i]);
    }
}

// 1 block x 256: CDF scan of the histogram, score all 128 candidates from the
// CDF (f64, exact on integer inputs), select top-8 by (score,k) lex, write params.
__global__ void k_cdftop(const float* __restrict__ mm, int mmb, float* __restrict__ W) {
    __shared__ uint32_t CC[NBIN + 1];
    __shared__ unsigned long long CQ[NBIN + 1];
    __shared__ uint32_t tc[TPB];
    __shared__ unsigned long long tq[TPB];
    __shared__ unsigned long long keys[128];
    __shared__ unsigned long long lmin2[2];
    __shared__ int sel[8];
    int tid = threadIdx.x;
    float xmin, xmax;
    mm_reduce(mm, mmb, tid, &xmin, &xmax);
    float R = xmax - xmin;

    const uint32_t* HC = (const uint32_t*)(W + OFF_HCNT);
    const unsigned long long* HQ = (const unsigned long long*)(W + OFF_HQS);
    const int BPT = NBIN / TPB;              // 8 bins per thread
    int base = tid * BPT;
    uint32_t cs = 0; unsigned long long qs = 0;
    #pragma unroll
    for (int b = 0; b < BPT; ++b) { cs += HC[base + b]; qs += HQ[base + b]; }
    tc[tid] = cs; tq[tid] = qs;
    __syncthreads();
    for (int off = 1; off < TPB; off <<= 1) {      // inclusive Hillis-Steele
        uint32_t ac = (tid >= off) ? tc[tid - off] : 0u;
        unsigned long long aq = (tid >= off) ? tq[tid - off] : 0ull;
        __syncthreads();
        tc[tid] += ac; tq[tid] += aq;
        __syncthreads();
    }
    uint32_t rc = tc[tid] - cs;                    // exclusive base
    unsigned long long rq = tq[tid] - qs;
    #pragma unroll
    for (int b = 0; b < BPT; ++b) {
        rc += HC[base + b]; rq += HQ[base + b];
        CC[base + b + 1] = rc; CQ[base + b + 1] = rq;
    }
    if (tid == 0) { CC[0] = 0u; CQ[0] = 0ull; }
    __syncthreads();

    if (tid < 128) {
        float nmi, nma;
        float4 p = cand_params(tid, xmin, xmax, &nmi, &nma);
        float s = p.y;
        int zi = (int)(0.0f - p.z);
        int lo = -zi, hi = 15 - zi;
        double A = 0.0, Bs = 0.0;
        double w2 = (double)R / 67108864.0;        // x ~= xmin + U*w2
        float binv = (float)NBIN / R;
        int j1 = 0;
        for (int m = lo; m <= hi; ++m) {
            int j2;
            if (m == hi) j2 = NBIN;
            else {
                float xs = ((float)m + 0.5f) * s;  // level boundary in x-space
                float fb = ceilf((xs - xmin) * binv);
                fb = fminf(fmaxf(fb, 0.0f), (float)NBIN);  // nan -> NBIN-safe
                j2 = (int)fb;
                j2 = (j2 > j1) ? j2 : j1;
            }
            if (j2 > j1) {
                uint32_t dn = CC[j2] - CC[j1];
                unsigned long long dq = CQ[j2] - CQ[j1];
                double Sx = (double)dn * (double)xmin + (double)dq * w2;
                A += (double)(m * m) * (double)dn;
                Bs += (double)m * Sx;
                j1 = j2;
            }
        }
        double T = (double)s * (double)s * A - 2.0 * (double)s * Bs;
        uint32_t tb = __float_as_uint((float)T);
        tb = (tb & 0x80000000u) ? ~tb : (tb | 0x80000000u);  // order-preserving encode
        unsigned long long key = (((unsigned long long)tb) << 32) | (uint32_t)tid;
        if (!(R > 0.0f)) key = (unsigned long long)tid;      // degenerate: keep k-order
        keys[tid] = key;
    }
    __syncthreads();
    for (int r = 0; r < 8; ++r) {                  // 8 rounds of lex-min selection
        unsigned long long kk = (tid < 128) ? keys[tid] : ~0ull;
        #pragma unroll
        for (int m = 32; m; m >>= 1) {
            unsigned long long o = __shfl_xor(kk, m, 64);
            kk = (o < kk) ? o : kk;
        }
        if (tid == 0 || tid == 64) lmin2[tid >> 6] = kk;
        __syncthreads();
        if (tid == 0) {
            unsigned long long g = (lmin2[0] < lmin2[1]) ? lmin2[0] : lmin2[1];
            int kid = (int)(g & 0x7fu);
            sel[r] = kid;
            keys[kid] = ~0ull;
        }
        __syncthreads();
    }
    if (tid < 8) {
        int kid = sel[tid];
        float nmi, nma;
        float4 p = cand_params(kid, xmin, xmax, &nmi, &nma);
        ((float4*)(W + OFF_TOP))[tid] = p;
        ((uint32_t*)(W + OFF_TOPK))[tid] = (uint32_t)kid;
    }
}

#define RQc(xv, qc, acc) { \
    float t_ = (xv) * qc.x; float r_ = rintf(t_); \
    float c_ = __builtin_amdgcn_fmed3f(r_, qc.z, qc.w); \
    float d_ = __builtin_fmaf(c_, qc.y, -(xv)); \
    acc = __builtin_fmaf(d_, d_, acc); }
#define RQ8(xv) { RQc(xv,q0,b0) RQc(xv,q1,b1) RQc(xv,q2,b2) RQc(xv,q3,b3) \
                  RQc(xv,q4,b4) RQc(xv,q5,b5) RQc(xv,q6,b6) RQc(xv,q7,b7) }

// exact per-element rescore of the 8 finalists (identical math to the proven
// full scorer). Params are wave-uniform -> SGPRs; VGPR stays low; coalesced.
__global__ __launch_bounds__(TPB) void k_rescore(const float* __restrict__ x, int n,
                                                 const float* __restrict__ W,
                                                 float* __restrict__ part) {
    const float4* P4 = (const float4*)(W + OFF_TOP);
    float4 q0 = P4[0], q1 = P4[1], q2 = P4[2], q3 = P4[3];
    float4 q4 = P4[4], q5 = P4[5], q6 = P4[6], q7 = P4[7];
    float b0 = 0, b1 = 0, b2 = 0, b3 = 0, b4 = 0, b5 = 0, b6 = 0, b7 = 0;
    int n4 = n >> 2;
    const float4* x4 = (const float4*)x;
    int gtid = blockIdx.x * TPB + threadIdx.x;
    int stride = gridDim.x * TPB;
    for (int i = gtid; i < n4; i += stride) {
        float4 v = x4[i];
        RQ8(v.x) RQ8(v.y) RQ8(v.z) RQ8(v.w)
    }
    for (int i = (n4 << 2) + gtid; i < n; i += stride) {
        float xv = x[i];
        RQ8(xv)
    }
    #pragma unroll
    for (int m = 32; m; m >>= 1) {
        b0 += __shfl_xor(b0, m, 64); b1 += __shfl_xor(b1, m, 64);
        b2 += __shfl_xor(b2, m, 64); b3 += __shfl_xor(b3, m, 64);
        b4 += __shfl_xor(b4, m, 64); b5 += __shfl_xor(b5, m, 64);
        b6 += __shfl_xor(b6, m, 64); b7 += __shfl_xor(b7, m, 64);
    }
    __shared__ float ws2[4][8];
    int wv = threadIdx.x >> 6;
    if ((threadIdx.x & 63) == 0) {
        ws2[wv][0] = b0; ws2[wv][1] = b1; ws2[wv][2] = b2; ws2[wv][3] = b3;
        ws2[wv][4] = b4; ws2[wv][5] = b5; ws2[wv][6] = b6; ws2[wv][7] = b7;
    }
    __syncthreads();
    if (threadIdx.x < 8) {
        part[(long)blockIdx.x * 8 + threadIdx.x] =
            (ws2[0][threadIdx.x] + ws2[1][threadIdx.x]) +
            (ws2[2][threadIdx.x] + ws2[3][threadIdx.x]);
    }
}

// 1 block x 256: fixed-order sum of RB x 8 partials, lex (S, k) argmin, output.
__global__ void k_fin(const float* __restrict__ mm, int mmb,
                      const float* __restrict__ part, const float* __restrict__ W,
                      float* __restrict__ out) {
    int tid = threadIdx.x;
    float xmin, xmax;
    mm_reduce(mm, mmb, tid, &xmin, &xmax);
    int c = tid >> 5, j = tid & 31;
    float s = 0.0f;
    for (int b = j; b < RB; b += 32) s += part[(long)b * 8 + c];  // fixed per-slice order
    __shared__ float red[8][32];
    __shared__ float Sc[8];
    red[c][j] = s;
    __syncthreads();
    if (j == 0) {
        float t = 0.0f;
        for (int jj = 0; jj < 32; ++jj) t += red[c][jj];          // fixed order
        Sc[c] = t;
    }
    __syncthreads();
    if (tid == 0) {
        const uint32_t* KK = (const uint32_t*)(W + OFF_TOPK);
        float bs = Sc[0]; uint32_t bk = KK[0];
        for (int cc = 1; cc < 8; ++cc) {
            uint32_t kc = KK[cc];
            if (Sc[cc] < bs || (Sc[cc] == bs && kc < bk)) { bs = Sc[cc]; bk = kc; }
        }
        float nmi, nma;
        (void)cand_params((int)bk, xmin, xmax, &nmi, &nma);
        out[0] = nmi;
        out[1] = nma;
    }
}

extern "C" void kernel_launch(void* const* d_in, const int* in_sizes, int n_in,
                              void* d_out, int out_size, void* d_ws, size_t ws_size,
                              hipStream_t stream) {
    const float* x = (const float*)d_in[0];
    int n = in_sizes[0];
    float* out = (float*)d_out;
    float* W = (float*)d_ws;

    int n4 = n >> 2;
    int mmb = (n4 + TPB - 1) / TPB;
    if (mmb > MMB) mmb = MMB;
    if (mmb < 1) mmb = 1;

    k_zero<<<(NBIN + TPB - 1) / TPB, TPB, 0, stream>>>(W);
    k_minmax<<<mmb, TPB, 0, stream>>>(x, n, W + OFF_MM);
    k_hist<<<HB, TPB, 0, stream>>>(x, n, W + OFF_MM, mmb, W);
    k_cdftop<<<1, TPB, 0, stream>>>(W + OFF_MM, mmb, W);
    k_rescore<<<RB, TPB, 0, stream>>>(x, n, W, W + OFF_RPART);
    k_fin<<<1, TPB, 0, stream>>>(W + OFF_MM, mmb, W + OFF_RPART, W, out);
}

// Round 9
// 65.553 us; speedup vs baseline: 3.2023x; 1.3313x over previous
//
#include <hip/hip_runtime.h>
#include <stdint.h>

#define TPB 256
#define MMB 1024        // minmax grid blocks / mm partial pairs
#define PB  512         // presel grid blocks (2048 waves = 2048 sampled chunks)
#define RB  1024        // rescore grid blocks
#define CHUNK 256       // elements per sampled chunk
#define NSAMP (PB * 4)  // sampled chunks (one per wave)

// d_ws float-index layout (~311 KB; ws proven >= 532 KB in earlier rounds):
//  [OFF_MM   + 2b] : minmax block partials {min,max}, b < MMB
//  [OFF_TOP  + 4r] : top-8 candidate params float4 {inv_s, s, lo, hi}
//  [OFF_TOPK + r]  : top-8 candidate ids (u32)
//  [OFF_ALLP + 4k] : all 128 candidate params
//  [OFF_NMIN + k] / [OFF_NMAX + k] : per-candidate new_min/new_max
//  [OFF_PSC  + k*PB + b] : presel partials (candidate-major)
//  [OFF_RPART+ b*8 + c]  : rescore per-block partials
#define OFF_MM     256
#define OFF_TOP    2304
#define OFF_TOPK   2336
#define OFF_ALLP   2560
#define OFF_NMIN   3072
#define OFF_NMAX   3200
#define OFF_PSC    4096
#define OFF_RPART  69632

__global__ __launch_bounds__(TPB) void k_minmax(const float* __restrict__ x, int n,
                                                float* __restrict__ mm) {
    int n4 = n >> 2;
    const float4* x4 = (const float4*)x;
    float mn = INFINITY, mx = -INFINITY;
    int idx = blockIdx.x * TPB + threadIdx.x;
    int stride = gridDim.x * TPB;
    for (int i = idx; i < n4; i += stride) {
        float4 v = x4[i];
        mn = fminf(mn, fminf(fminf(v.x, v.y), fminf(v.z, v.w)));
        mx = fmaxf(mx, fmaxf(fmaxf(v.x, v.y), fmaxf(v.z, v.w)));
    }
    for (int i = (n4 << 2) + idx; i < n; i += stride) {
        float v = x[i];
        mn = fminf(mn, v);
        mx = fmaxf(mx, v);
    }
    #pragma unroll
    for (int m = 32; m; m >>= 1) {
        mn = fminf(mn, __shfl_xor(mn, m, 64));
        mx = fmaxf(mx, __shfl_xor(mx, m, 64));
    }
    __shared__ float smn[4], smx[4];
    int wv = threadIdx.x >> 6;
    if ((threadIdx.x & 63) == 0) { smn[wv] = mn; smx[wv] = mx; }
    __syncthreads();
    if (threadIdx.x == 0) {
        mn = fminf(fminf(smn[0], smn[1]), fminf(smn[2], smn[3]));
        mx = fmaxf(fmaxf(smx[0], smx[1]), fmaxf(smx[2], smx[3]));
        mm[2 * blockIdx.x + 0] = mn;
        mm[2 * blockIdx.x + 1] = mx;
    }
}

// exact reference fp32 order
__device__ __forceinline__ float4 cand_params(int k, float xmin, float xmax,
                                              float* nmin_out, float* nmax_out) {
    float xrange = xmax - xmin;
    int ii = k >> 4;                       // 0..7  (i = ii+1)
    float zpf = (float)(k & 15);
    float tmp_max = xrange / 8.0f * (float)(ii + 1);
    float tmp_delta = tmp_max / 15.0f;
    float shift = zpf * tmp_delta;
    float new_min = fmaxf(0.0f - shift, xmin);
    float new_max = fminf(tmp_max - shift, xmax);
    float min_neg = fminf(new_min, 0.0f);
    float max_pos = fmaxf(new_max, 0.0f);
    float scale = fmaxf((max_pos - min_neg) / 15.0f, 1e-8f);
    float zp = 0.0f - rintf(min_neg / scale);
    zp = fminf(fmaxf(zp, 0.0f), 15.0f);
    float4 p;
    p.x = 1.0f / scale;      // inv_s
    p.y = scale;             // s
    p.z = 0.0f - zp;         // lo
    p.w = 15.0f - zp;        // hi
    *nmin_out = new_min;
    *nmax_out = new_max;
    return p;
}

__device__ __forceinline__ void mm_reduce(const float* __restrict__ mm, int mmb,
                                          int tid, float* xmin_o, float* xmax_o) {
    __shared__ float smn[4], smx[4];
    float mn = INFINITY, mx = -INFINITY;
    for (int e = tid; e < mmb; e += TPB) {
        mn = fminf(mn, mm[2 * e + 0]);
        mx = fmaxf(mx, mm[2 * e + 1]);
    }
    #pragma unroll
    for (int m = 32; m; m >>= 1) {
        mn = fminf(mn, __shfl_xor(mn, m, 64));
        mx = fmaxf(mx, __shfl_xor(mx, m, 64));
    }
    int wv = tid >> 6;
    if ((tid & 63) == 0) { smn[wv] = mn; smx[wv] = mx; }
    __syncthreads();
    *xmin_o = fminf(fminf(smn[0], smn[1]), fminf(smn[2], smn[3]));
    *xmax_o = fmaxf(fmaxf(smx[0], smx[1]), fmaxf(smx[2], smx[3]));
}

#define QUANT1(xv) { \
    float t0_ = (xv) * p0.x; float r0_ = rintf(t0_); \
    float c0_ = __builtin_amdgcn_fmed3f(r0_, p0.z, p0.w); \
    float d0_ = __builtin_fmaf(c0_, p0.y, -(xv)); \
    a0 = __builtin_fmaf(d0_, d0_, a0); \
    float t1_ = (xv) * p1.x; float r1_ = rintf(t1_); \
    float c1_ = __builtin_amdgcn_fmed3f(r1_, p1.z, p1.w); \
    float d1_ = __builtin_fmaf(c1_, p1.y, -(xv)); \
    a1 = __builtin_fmaf(d1_, d1_, a1); }
#define QUANT4(V) { QUANT1(V.x) QUANT1(V.y) QUANT1(V.z) QUANT1(V.w) }

// approximate preselection: score all 128 candidates (2 per lane) on a
// deterministic 1/16 chunk-sample via the proven LDS-broadcast body.
// Block 0 / wave 0 also publishes all 128 params + new_min/new_max.
__global__ __launch_bounds__(TPB) void k_presel(const float* __restrict__ x, int n,
                                                const float* __restrict__ mm, int mmb,
                                                float* __restrict__ W, int nwc,
                                                int gstride) {
    __shared__ float ls[4][CHUNK];
    __shared__ float wsum[4][128];
    int tid = threadIdx.x, lane = tid & 63;
    int wv = __builtin_amdgcn_readfirstlane(threadIdx.x >> 6);
    float xmin, xmax;
    mm_reduce(mm, mmb, tid, &xmin, &xmax);
    float nmi0, nma0, nmi1, nma1;
    float4 p0 = cand_params(2 * lane + 0, xmin, xmax, &nmi0, &nma0);
    float4 p1 = cand_params(2 * lane + 1, xmin, xmax, &nmi1, &nma1);
    if (blockIdx.x == 0 && tid < 64) {
        ((float4*)(W + OFF_ALLP))[2 * lane + 0] = p0;
        ((float4*)(W + OFF_ALLP))[2 * lane + 1] = p1;
        W[OFF_NMIN + 2 * lane + 0] = nmi0;
        W[OFF_NMIN + 2 * lane + 1] = nmi1;
        W[OFF_NMAX + 2 * lane + 0] = nma0;
        W[OFF_NMAX + 2 * lane + 1] = nma1;
    }
    float a0 = 0.0f, a1 = 0.0f;
    long nl = (long)n;

    int sc = blockIdx.x * 4 + wv;             // one sampled chunk per wave
    long g = (long)sc * gstride;              // global chunk index
    if (g < (long)nwc) {
        long base = g * CHUNK;
        long e = base + (long)lane * 4;
        float4 v;
        if (base + CHUNK <= nl) {
            v = *(const float4*)(x + e);
        } else {
            v.x = (e + 0 < nl) ? x[e + 0] : 0.0f;  // pad scores 0 for every cand
            v.y = (e + 1 < nl) ? x[e + 1] : 0.0f;
            v.z = (e + 2 < nl) ? x[e + 2] : 0.0f;
            v.w = (e + 3 < nl) ? x[e + 3] : 0.0f;
        }
        *(float4*)(&ls[wv][lane * 4]) = v;
        // wave-private region: intra-wave write->read ordering only
        asm volatile("s_waitcnt lgkmcnt(0)" ::: "memory");
        __builtin_amdgcn_sched_barrier(0);
        const float4* l4 = (const float4*)(&ls[wv][0]);
        #pragma unroll 4
        for (int i = 0; i < CHUNK / 4; ++i) {
            float4 u = l4[i];
            QUANT4(u)
        }
    }
    wsum[wv][2 * lane + 0] = a0;
    wsum[wv][2 * lane + 1] = a1;
    __syncthreads();
    if (tid < 128) {
        W[OFF_PSC + (long)tid * PB + blockIdx.x] =
            (wsum[0][tid] + wsum[1][tid]) + (wsum[2][tid] + wsum[3][tid]);
    }
}

// 1 block x 1024: reduce presel partials (fixed slice order + fixed tree),
// select top-8 by (score,k) lex-min, publish their params + ids.
__global__ void k_top(float* __restrict__ W) {
    __shared__ float red[128][8];
    __shared__ float sc[128];
    __shared__ unsigned long long keys[128];
    __shared__ unsigned long long lmin[16];
    __shared__ int sel[8];
    int t = threadIdx.x;
    int k = t >> 3, j = t & 7;
    const float* part = W + OFF_PSC;
    float s = 0.0f;
    for (int b = j; b < PB; b += 8) s += part[(long)k * PB + b];  // fixed order
    red[k][j] = s;
    __syncthreads();
    if (j == 0) {
        sc[k] = ((red[k][0] + red[k][1]) + (red[k][2] + red[k][3]))
              + ((red[k][4] + red[k][5]) + (red[k][6] + red[k][7]));
    }
    __syncthreads();
    if (t < 128) {
        uint32_t tb = __float_as_uint(sc[t]);
        tb = (tb & 0x80000000u) ? ~tb : (tb | 0x80000000u);  // order-preserving
        keys[t] = (((unsigned long long)tb) << 32) | (unsigned)t;
    }
    __syncthreads();
    int wv = t >> 6;
    for (int r = 0; r < 8; ++r) {
        unsigned long long kk = (t < 128) ? keys[t] : ~0ull;
        #pragma unroll
        for (int m = 32; m; m >>= 1) {
            unsigned long long o = __shfl_xor(kk, m, 64);
            kk = (o < kk) ? o : kk;
        }
        if ((t & 63) == 0) lmin[wv] = kk;
        __syncthreads();
        if (t == 0) {
            unsigned long long g = (lmin[0] < lmin[1]) ? lmin[0] : lmin[1];
            int kid = (int)(g & 0x7fu);
            sel[r] = kid;
            keys[kid] = ~0ull;
        }
        __syncthreads();
    }
    if (t < 8) {
        int kid = sel[t];
        ((float4*)(W + OFF_TOP))[t] = ((const float4*)(W + OFF_ALLP))[kid];
        ((uint32_t*)(W + OFF_TOPK))[t] = (uint32_t)kid;
    }
}

#define RQc(xv, qc, acc) { \
    float t_ = (xv) * qc.x; float r_ = rintf(t_); \
    float c_ = __builtin_amdgcn_fmed3f(r_, qc.z, qc.w); \
    float d_ = __builtin_fmaf(c_, qc.y, -(xv)); \
    acc = __builtin_fmaf(d_, d_, acc); }
#define RQ8(xv) { RQc(xv,q0,b0) RQc(xv,q1,b1) RQc(xv,q2,b2) RQc(xv,q3,b3) \
                  RQc(xv,q4,b4) RQc(xv,q5,b5) RQc(xv,q6,b6) RQc(xv,q7,b7) }

// exact per-element rescore of the 8 finalists (proven identical math).
__global__ __launch_bounds__(TPB) void k_rescore(const float* __restrict__ x, int n,
                                                 const float* __restrict__ W,
                                                 float* __restrict__ part) {
    const float4* P4 = (const float4*)(W + OFF_TOP);
    float4 q0 = P4[0], q1 = P4[1], q2 = P4[2], q3 = P4[3];
    float4 q4 = P4[4], q5 = P4[5], q6 = P4[6], q7 = P4[7];
    float b0 = 0, b1 = 0, b2 = 0, b3 = 0, b4 = 0, b5 = 0, b6 = 0, b7 = 0;
    int n4 = n >> 2;
    const float4* x4 = (const float4*)x;
    int gtid = blockIdx.x * TPB + threadIdx.x;
    int stride = gridDim.x * TPB;
    for (int i = gtid; i < n4; i += stride) {
        float4 v = x4[i];
        RQ8(v.x) RQ8(v.y) RQ8(v.z) RQ8(v.w)
    }
    for (int i = (n4 << 2) + gtid; i < n; i += stride) {
        float xv = x[i];
        RQ8(xv)
    }
    #pragma unroll
    for (int m = 32; m; m >>= 1) {
        b0 += __shfl_xor(b0, m, 64); b1 += __shfl_xor(b1, m, 64);
        b2 += __shfl_xor(b2, m, 64); b3 += __shfl_xor(b3, m, 64);
        b4 += __shfl_xor(b4, m, 64); b5 += __shfl_xor(b5, m, 64);
        b6 += __shfl_xor(b6, m, 64); b7 += __shfl_xor(b7, m, 64);
    }
    __shared__ float ws2[4][8];
    int wv = threadIdx.x >> 6;
    if ((threadIdx.x & 63) == 0) {
        ws2[wv][0] = b0; ws2[wv][1] = b1; ws2[wv][2] = b2; ws2[wv][3] = b3;
        ws2[wv][4] = b4; ws2[wv][5] = b5; ws2[wv][6] = b6; ws2[wv][7] = b7;
    }
    __syncthreads();
    if (threadIdx.x < 8) {
        part[(long)blockIdx.x * 8 + threadIdx.x] =
            (ws2[0][threadIdx.x] + ws2[1][threadIdx.x]) +
            (ws2[2][threadIdx.x] + ws2[3][threadIdx.x]);
    }
}

// 1 block x 256: fixed-order sum of RB x 8 partials, lex (S,k) argmin, output
// new_min/new_max by table lookup.
__global__ void k_fin(const float* __restrict__ part, const float* __restrict__ W,
                      float* __restrict__ out) {
    __shared__ float red[8][32];
    __shared__ float Sc[8];
    int tid = threadIdx.x;
    int c = tid >> 5, j = tid & 31;
    float s = 0.0f;
    for (int b = j; b < RB; b += 32) s += part[(long)b * 8 + c];  // fixed order
    red[c][j] = s;
    __syncthreads();
    if (j == 0) {
        float t = 0.0f;
        for (int jj = 0; jj < 32; ++jj) t += red[c][jj];          // fixed order
        Sc[c] = t;
    }
    __syncthreads();
    if (tid == 0) {
        const uint32_t* KK = (const uint32_t*)(W + OFF_TOPK);
        float bs = Sc[0]; uint32_t bk = KK[0];
        for (int cc = 1; cc < 8; ++cc) {
            uint32_t kc = KK[cc];
            if (Sc[cc] < bs || (Sc[cc] == bs && kc < bk)) { bs = Sc[cc]; bk = kc; }
        }
        out[0] = W[OFF_NMIN + bk];
        out[1] = W[OFF_NMAX + bk];
    }
}

extern "C" void kernel_launch(void* const* d_in, const int* in_sizes, int n_in,
                              void* d_out, int out_size, void* d_ws, size_t ws_size,
                              hipStream_t stream) {
    const float* x = (const float*)d_in[0];
    int n = in_sizes[0];
    float* out = (float*)d_out;
    float* W = (float*)d_ws;

    int n4 = n >> 2;
    int mmb = (n4 + TPB - 1) / TPB;
    if (mmb > MMB) mmb = MMB;
    if (mmb < 1) mmb = 1;

    int nwc = (n + CHUNK - 1) / CHUNK;
    int gstride = nwc / NSAMP;
    if (gstride < 1) gstride = 1;

    k_minmax<<<mmb, TPB, 0, stream>>>(x, n, W + OFF_MM);
    k_presel<<<PB, TPB, 0, stream>>>(x, n, W + OFF_MM, mmb, W, nwc, gstride);
    k_top<<<1, 1024, 0, stream>>>(W);
    k_rescore<<<RB, TPB, 0, stream>>>(x, n, W, W + OFF_RPART);
    k_fin<<<1, TPB, 0, stream>>>(W + OFF_RPART, W, out);
}